// Round 14
// baseline (39.496 us; speedup 1.0000x reference)
//
#include <hip/hip_runtime.h>
#include <math.h>

#define NH 128   // hidden
#define ND 16    // per-particle dim
#define NF 112   // 7*ND
#define NB 128   // batch

#define CC 2.8853900817779268f   // 2*log2(e): exp2(CC*s) = e^{2s}

typedef float f2 __attribute__((ext_vector_type(2)));

__device__ __forceinline__ float rcpf(float x) { return __builtin_amdgcn_rcpf(x); }

#define GLD(i, j) (*(const f2*)&psh[((i) * 7 + (j)) * NH + (lane << 1)])

// Pair (a,b) at pos 5,6 under prefix-exp E4: +/- (ea-eb)/((1+ea)(1+eb)); x2 at finalize
#define PAIRP(E4v, A5, A6, B5, B6) do {            \
    f2 ea = (E4v) * ((A5) * (B6));                 \
    f2 eb = (E4v) * ((B5) * (A6));                 \
    f2 num = ea - eb;                              \
    f2 den = (ea + 1.0f) * (eb + 1.0f);            \
    f2 rd; rd.x = rcpf(den.x); rd.y = rcpf(den.y); \
    accG.x = fmaf(num.x, rd.x, accG.x);            \
    accG.y = fmaf(num.y, rd.y, accG.y);            \
  } while (0)

#define PAIRM(E4v, A5, A6, B5, B6) do {            \
    f2 ea = (E4v) * ((A5) * (B6));                 \
    f2 eb = (E4v) * ((B5) * (A6));                 \
    f2 num = ea - eb;                              \
    f2 den = (ea + 1.0f) * (eb + 1.0f);            \
    f2 rd; rd.x = rcpf(den.x); rd.y = rcpf(den.y); \
    accG.x = fmaf(-num.x, rd.x, accG.x);           \
    accG.y = fmaf(-num.y, rd.y, accG.y);           \
  } while (0)

// pos3-element G3 under trio prefix E2; pos4 over sorted {p,q,r}, signs +,-,+
#define T3P(G3, M4P, M4Q, M4R, A5, A6, B5, B6, C5, C6) do {  \
    f2 E3 = E2 * (G3);                                       \
    PAIRP(E3 * (M4P), B5, B6, C5, C6);                       \
    PAIRM(E3 * (M4Q), A5, A6, C5, C6);                       \
    PAIRP(E3 * (M4R), A5, A6, B5, B6);                       \
  } while (0)

#define T3M(G3, M4P, M4Q, M4R, A5, A6, B5, B6, C5, C6) do {  \
    f2 E3 = E2 * (G3);                                       \
    PAIRM(E3 * (M4P), B5, B6, C5, C6);                       \
    PAIRP(E3 * (M4Q), A5, A6, C5, C6);                       \
    PAIRM(E3 * (M4R), A5, A6, B5, B6);                       \
  } while (0)

// Trio: t2-element Q2J at pos 2; remaining sorted {a,b,c,d} fill pos 3..6.
// TA/TB = T3P/T3M (even trio) or swapped (odd), folding (-1)^trio.
#define TRIO(Q2J, TA, TB, g3a, g3b, g3c, g3d, m4a, m4b, m4c, m4d,       \
             p5a, p6a, p5b, p6b, p5c, p6c, p5d, p6d) do {               \
    f2 E2 = E1 * (Q2J);                                                 \
    TA(g3a, m4b, m4c, m4d, p5b, p6b, p5c, p6c, p5d, p6d);               \
    TB(g3b, m4a, m4c, m4d, p5a, p6a, p5c, p6c, p5d, p6d);               \
    TA(g3c, m4a, m4b, m4d, p5a, p6a, p5b, p6b, p5d, p6d);               \
    TB(g3d, m4a, m4b, m4c, p5a, p6a, p5b, p6b, p5c, p6c);               \
  } while (0)

// 448 threads = 7 waves; 3 blocks per (leaf,b) -> 21 slots x exactly 2 groups
extern "C" __global__ void __launch_bounds__(448, 4)
antisym_leaf_kernel(const float* __restrict__ x0, const float* __restrict__ x1,
                    const float* __restrict__ W0, const float* __restrict__ b0,
                    const float* __restrict__ V0,
                    const float* __restrict__ W1, const float* __restrict__ b1,
                    const float* __restrict__ V1,
                    float* __restrict__ ws) {
  __shared__ float psh[49 * NH];   // P[i][j][h] = exp(2*G[i][j][h])
  __shared__ float xs[NF];
  __shared__ float red[7];

  const int tid   = threadIdx.x;
  const int bid   = blockIdx.x;         // [0, 768): leaf*384 + split*128 + b
  const int leaf  = bid / 384;
  const int rem   = bid - leaf * 384;
  const int split = rem >> 7;           // 0..2
  const int b     = rem & 127;

  const float* xL = leaf ? x1 : x0;
  const float* WL = leaf ? W1 : W0;
  const float* bL = leaf ? b1 : b0;
  const float* vL = leaf ? V1 : V0;

  // ---- Phase A: stage x row, build P[i][j][h] = exp(2*x_j . W_i[:,h]) in LDS ----
  if (tid < NF) xs[tid] = xL[b * NF + tid];
  __syncthreads();

  for (int idx = tid; idx < 49 * NH; idx += 448) {
    int h  = idx & (NH - 1);
    int ij = idx >> 7;          // 0..48
    int i  = ij / 7;
    int j  = ij - 7 * i;
    const float* wp = WL + i * ND * NH + h;   // coalesced over h
    const float* xp = xs + j * ND;
    float v = 0.f;
#pragma unroll
    for (int k = 0; k < ND; ++k) v = fmaf(xp[k], wp[k * NH], v);
    psh[idx] = __builtin_amdgcn_exp2f(v * CC);
  }
  __syncthreads();

  // ---- Phase B: 42 groups = 21 slots x exactly 2 (zero imbalance) ----
  const int lane = tid & 63;
  const int wid  = tid >> 6;            // 0..6
  const int slot = split * 7 + wid;     // 0..20

  f2 bias2 = ((const f2*)bL)[lane];
  f2 V2    = ((const f2*)vL)[lane];
  f2 Eb;
  Eb.x = __builtin_amdgcn_exp2f(bias2.x * CC);
  Eb.y = __builtin_amdgcn_exp2f(bias2.y * CC);
  f2 acc = {0.f, 0.f};

#pragma unroll 1
  for (int k = 0; k < 2; ++k) {
    int g = slot + k * 21;              // covers 0..41 exactly once
    int t0 = g / 6;
    int c1 = g - 6 * t0;
    int t1 = c1 + (c1 >= t0 ? 1 : 0);
    float sg1 = ((t0 + c1) & 1) ? -1.f : 1.f;

    int rm = 0x7F & ~((1 << t0) | (1 << t1));
    int r0 = __ffs(rm) - 1; rm &= rm - 1;
    int r1 = __ffs(rm) - 1; rm &= rm - 1;
    int r2 = __ffs(rm) - 1; rm &= rm - 1;
    int r3 = __ffs(rm) - 1; rm &= rm - 1;
    int r4 = __ffs(rm) - 1;

    // 27 ds_read_b64, one batch per group (values reused 4-12x below)
    f2 E1  = Eb * GLD(0, t0) * GLD(1, t1);
    f2 q20 = GLD(2, r0), q21 = GLD(2, r1), q22 = GLD(2, r2), q23 = GLD(2, r3), q24 = GLD(2, r4);
    f2 g30 = GLD(3, r0), g31 = GLD(3, r1), g32 = GLD(3, r2), g33 = GLD(3, r3), g34 = GLD(3, r4);
    f2 m40 = GLD(4, r0), m41 = GLD(4, r1), m42 = GLD(4, r2), m43 = GLD(4, r3), m44 = GLD(4, r4);
    f2 q50 = GLD(5, r0), q51 = GLD(5, r1), q52 = GLD(5, r2), q53 = GLD(5, r3), q54 = GLD(5, r4);
    f2 q60 = GLD(6, r0), q61 = GLD(6, r1), q62 = GLD(6, r2), q63 = GLD(6, r3), q64 = GLD(6, r4);

    f2 accG = {0.f, 0.f};
    TRIO(q20, T3P, T3M, g31, g32, g33, g34, m41, m42, m43, m44,
         q51, q61, q52, q62, q53, q63, q54, q64);
    TRIO(q21, T3M, T3P, g30, g32, g33, g34, m40, m42, m43, m44,
         q50, q60, q52, q62, q53, q63, q54, q64);
    TRIO(q22, T3P, T3M, g30, g31, g33, g34, m40, m41, m43, m44,
         q50, q60, q51, q61, q53, q63, q54, q64);
    TRIO(q23, T3M, T3P, g30, g31, g32, g34, m40, m41, m42, m44,
         q50, q60, q51, q61, q52, q62, q54, q64);
    TRIO(q24, T3P, T3M, g30, g31, g32, g33, m40, m41, m42, m43,
         q50, q60, q51, q61, q52, q62, q53, q63);

    acc.x = fmaf(sg1, accG.x, acc.x);
    acc.y = fmaf(sg1, accG.y, acc.y);
  }

  // ---- Reduce: partial psi = sum_h V[h] * acc[h] (factor 2 in finalize) ----
  float part = V2.x * acc.x + V2.y * acc.y;
#pragma unroll
  for (int off = 32; off > 0; off >>= 1) part += __shfl_xor(part, off, 64);
  if (lane == 0) red[wid] = part;
  __syncthreads();
  if (tid == 0) {
    float tot = 0.f;
#pragma unroll
    for (int w = 0; w < 7; ++w) tot += red[w];
    ws[leaf * 384 + split * 128 + b] = tot;
  }
}

extern "C" __global__ void finalize_kernel(const float* __restrict__ ws,
                                           float* __restrict__ out) {
  int t = threadIdx.x;
  if (t < NB) {
    float p0 = 2.0f * (ws[t] + ws[128 + t] + ws[256 + t]);
    float p1 = 2.0f * (ws[384 + t] + ws[512 + t] + ws[640 + t]);
    float s0 = (p0 > 0.f) ? 1.f : ((p0 < 0.f) ? -1.f : 0.f);
    float s1 = (p1 > 0.f) ? 1.f : ((p1 < 0.f) ? -1.f : 0.f);
    out[t]      = s0 * s1;                            // sign
    out[NB + t] = logf(fabsf(p0)) + logf(fabsf(p1));  // logabs
  }
}

extern "C" void kernel_launch(void* const* d_in, const int* in_sizes, int n_in,
                              void* d_out, int out_size, void* d_ws, size_t ws_size,
                              hipStream_t stream) {
  const float* x0 = (const float*)d_in[0];
  const float* x1 = (const float*)d_in[1];
  const float* W0 = (const float*)d_in[2];
  const float* b0 = (const float*)d_in[3];
  const float* V0 = (const float*)d_in[4];
  // d_in[5] = c0: cancels under antisymmetrization (sum of signs == 0)
  const float* W1 = (const float*)d_in[6];
  const float* b1 = (const float*)d_in[7];
  const float* V1 = (const float*)d_in[8];
  // d_in[9] = c1: cancels

  float* ws  = (float*)d_ws;      // 768 floats: psi partials [leaf][split][b]
  float* out = (float*)d_out;     // 256 floats: sign[128], logabs[128]

  antisym_leaf_kernel<<<768, 448, 0, stream>>>(x0, x1, W0, b0, V0, W1, b1, V1, ws);
  finalize_kernel<<<1, NB, 0, stream>>>(ws, out);
}

// Round 15
// 30.898 us; speedup vs baseline: 1.2783x; 1.2783x over previous
//
#include <hip/hip_runtime.h>
#include <math.h>

#define NH 128   // hidden
#define ND 16    // per-particle dim
#define NF 112   // 7*ND
#define NB 128   // batch

#define CC 2.8853900817779268f   // 2*log2(e): exp2(CC*s) = e^{2s}

typedef float f2 __attribute__((ext_vector_type(2)));

__device__ __forceinline__ float rcpf(float x) { return __builtin_amdgcn_rcpf(x); }

#define GLD(i, j) (*(const f2*)&psh[((i) * 7 + (j)) * NH + (lane << 1)])

// Pair (a,b) at pos 5,6 under prefix-exp E4: +/- (ea-eb)/((1+ea)(1+eb)); x2 at finalize
#define PAIRP(E4v, A5, A6, B5, B6) do {            \
    f2 ea = (E4v) * ((A5) * (B6));                 \
    f2 eb = (E4v) * ((B5) * (A6));                 \
    f2 num = ea - eb;                              \
    f2 den = (ea + 1.0f) * (eb + 1.0f);            \
    f2 rd; rd.x = rcpf(den.x); rd.y = rcpf(den.y); \
    accG.x = fmaf(num.x, rd.x, accG.x);            \
    accG.y = fmaf(num.y, rd.y, accG.y);            \
  } while (0)

#define PAIRM(E4v, A5, A6, B5, B6) do {            \
    f2 ea = (E4v) * ((A5) * (B6));                 \
    f2 eb = (E4v) * ((B5) * (A6));                 \
    f2 num = ea - eb;                              \
    f2 den = (ea + 1.0f) * (eb + 1.0f);            \
    f2 rd; rd.x = rcpf(den.x); rd.y = rcpf(den.y); \
    accG.x = fmaf(-num.x, rd.x, accG.x);           \
    accG.y = fmaf(-num.y, rd.y, accG.y);           \
  } while (0)

// pos3-element G3 under trio prefix E2; pos4 over sorted {p,q,r}, signs +,-,+
#define T3P(G3, M4P, M4Q, M4R, A5, A6, B5, B6, C5, C6) do {  \
    f2 E3 = E2 * (G3);                                       \
    PAIRP(E3 * (M4P), B5, B6, C5, C6);                       \
    PAIRM(E3 * (M4Q), A5, A6, C5, C6);                       \
    PAIRP(E3 * (M4R), A5, A6, B5, B6);                       \
  } while (0)

#define T3M(G3, M4P, M4Q, M4R, A5, A6, B5, B6, C5, C6) do {  \
    f2 E3 = E2 * (G3);                                       \
    PAIRM(E3 * (M4P), B5, B6, C5, C6);                       \
    PAIRP(E3 * (M4Q), A5, A6, C5, C6);                       \
    PAIRM(E3 * (M4R), A5, A6, B5, B6);                       \
  } while (0)

// Trio: t2-element Q2J at pos 2; remaining sorted {a,b,c,d} fill pos 3..6.
// TA/TB = T3P/T3M (even trio) or swapped (odd), folding (-1)^trio.
#define TRIO(Q2J, TA, TB, g3a, g3b, g3c, g3d, m4a, m4b, m4c, m4d,       \
             p5a, p6a, p5b, p6b, p5c, p6c, p5d, p6d) do {               \
    f2 E2 = E1 * (Q2J);                                                 \
    TA(g3a, m4b, m4c, m4d, p5b, p6b, p5c, p6c, p5d, p6d);               \
    TB(g3b, m4a, m4c, m4d, p5a, p6a, p5c, p6c, p5d, p6d);               \
    TA(g3c, m4a, m4b, m4d, p5a, p6a, p5b, p6b, p5d, p6d);               \
    TB(g3d, m4a, m4b, m4c, p5a, p6a, p5b, p6b, p5c, p6c);               \
  } while (0)

extern "C" __global__ void __launch_bounds__(512, 4)
antisym_leaf_kernel(const float* __restrict__ x0, const float* __restrict__ x1,
                    const float* __restrict__ W0, const float* __restrict__ b0,
                    const float* __restrict__ V0,
                    const float* __restrict__ W1, const float* __restrict__ b1,
                    const float* __restrict__ V1,
                    float* __restrict__ ws) {
  __shared__ float psh[49 * NH];   // P[i][j][h] = exp(2*G[i][j][h])
  __shared__ float xs[NF];
  __shared__ float red[8];

  const int tid  = threadIdx.x;
  const int bid  = blockIdx.x;          // [0, 512)
  const int leaf = bid >> 8;
  const int half = (bid >> 7) & 1;
  const int b    = bid & 127;

  const float* xL = leaf ? x1 : x0;
  const float* WL = leaf ? W1 : W0;
  const float* bL = leaf ? b1 : b0;
  const float* vL = leaf ? V1 : V0;

  // ---- Phase A: stage x row, build P[i][j][h] = exp(2*x_j . W_i[:,h]) in LDS ----
  if (tid < NF) xs[tid] = xL[b * NF + tid];
  __syncthreads();

  for (int idx = tid; idx < 49 * NH; idx += 512) {
    int h  = idx & (NH - 1);
    int ij = idx >> 7;          // 0..48
    int i  = ij / 7;
    int j  = ij - 7 * i;
    const float* wp = WL + i * ND * NH + h;   // coalesced over h
    const float* xp = xs + j * ND;
    float v = 0.f;
#pragma unroll
    for (int k = 0; k < ND; ++k) v = fmaf(xp[k], wp[k * NH], v);
    psh[idx] = __builtin_amdgcn_exp2f(v * CC);
  }
  __syncthreads();

  // ---- Phase B: 42 groups over 16 slots (R6 layout), load-batch fenced ----
  const int lane = tid & 63;
  const int wid  = tid >> 6;            // 0..7
  const int slot = (half << 3) | wid;   // 0..15

  f2 bias2 = ((const f2*)bL)[lane];
  f2 V2    = ((const f2*)vL)[lane];
  f2 Eb;
  Eb.x = __builtin_amdgcn_exp2f(bias2.x * CC);
  Eb.y = __builtin_amdgcn_exp2f(bias2.y * CC);
  f2 acc = {0.f, 0.f};

#pragma unroll 1
  for (int k = 0; k < 3; ++k) {
    int g = slot + (k << 4);            // group id
    if (g >= 42) break;
    int t0 = g / 6;
    int c1 = g - 6 * t0;
    int t1 = c1 + (c1 >= t0 ? 1 : 0);
    float sg1 = ((t0 + c1) & 1) ? -1.f : 1.f;

    int rm = 0x7F & ~((1 << t0) | (1 << t1));
    int r0 = __ffs(rm) - 1; rm &= rm - 1;
    int r1 = __ffs(rm) - 1; rm &= rm - 1;
    int r2 = __ffs(rm) - 1; rm &= rm - 1;
    int r3 = __ffs(rm) - 1; rm &= rm - 1;
    int r4 = __ffs(rm) - 1;

    // 27 ds_read_b64 issued as one contiguous batch...
    f2 E1  = Eb * GLD(0, t0) * GLD(1, t1);
    f2 q20 = GLD(2, r0), q21 = GLD(2, r1), q22 = GLD(2, r2), q23 = GLD(2, r3), q24 = GLD(2, r4);
    f2 g30 = GLD(3, r0), g31 = GLD(3, r1), g32 = GLD(3, r2), g33 = GLD(3, r3), g34 = GLD(3, r4);
    f2 m40 = GLD(4, r0), m41 = GLD(4, r1), m42 = GLD(4, r2), m43 = GLD(4, r3), m44 = GLD(4, r4);
    f2 q50 = GLD(5, r0), q51 = GLD(5, r1), q52 = GLD(5, r2), q53 = GLD(5, r3), q54 = GLD(5, r4);
    f2 q60 = GLD(6, r0), q61 = GLD(6, r1), q62 = GLD(6, r2), q63 = GLD(6, r3), q64 = GLD(6, r4);

    // ...and fenced: the scheduler may NOT sink any of them into the compute
    // below (R5 showed it otherwise re-serializes load->wait->use per value).
    __builtin_amdgcn_sched_barrier(0);

    f2 accG = {0.f, 0.f};
    TRIO(q20, T3P, T3M, g31, g32, g33, g34, m41, m42, m43, m44,
         q51, q61, q52, q62, q53, q63, q54, q64);
    TRIO(q21, T3M, T3P, g30, g32, g33, g34, m40, m42, m43, m44,
         q50, q60, q52, q62, q53, q63, q54, q64);
    TRIO(q22, T3P, T3M, g30, g31, g33, g34, m40, m41, m43, m44,
         q50, q60, q51, q61, q53, q63, q54, q64);
    TRIO(q23, T3M, T3P, g30, g31, g32, g34, m40, m41, m42, m44,
         q50, q60, q51, q61, q52, q62, q54, q64);
    TRIO(q24, T3P, T3M, g30, g31, g32, g33, m40, m41, m42, m43,
         q50, q60, q51, q61, q52, q62, q53, q63);

    acc.x = fmaf(sg1, accG.x, acc.x);
    acc.y = fmaf(sg1, accG.y, acc.y);
  }

  // ---- Reduce: partial psi = sum_h V[h] * acc[h] (factor 2 in finalize) ----
  float part = V2.x * acc.x + V2.y * acc.y;
#pragma unroll
  for (int off = 32; off > 0; off >>= 1) part += __shfl_xor(part, off, 64);
  if (lane == 0) red[wid] = part;
  __syncthreads();
  if (tid == 0) {
    float tot = 0.f;
#pragma unroll
    for (int w = 0; w < 8; ++w) tot += red[w];
    ws[leaf * 256 + half * 128 + b] = tot;
  }
}

extern "C" __global__ void finalize_kernel(const float* __restrict__ ws,
                                           float* __restrict__ out) {
  int t = threadIdx.x;
  if (t < NB) {
    float p0 = 2.0f * (ws[t] + ws[128 + t]);
    float p1 = 2.0f * (ws[256 + t] + ws[384 + t]);
    float s0 = (p0 > 0.f) ? 1.f : ((p0 < 0.f) ? -1.f : 0.f);
    float s1 = (p1 > 0.f) ? 1.f : ((p1 < 0.f) ? -1.f : 0.f);
    out[t]      = s0 * s1;                            // sign
    out[NB + t] = logf(fabsf(p0)) + logf(fabsf(p1));  // logabs
  }
}

extern "C" void kernel_launch(void* const* d_in, const int* in_sizes, int n_in,
                              void* d_out, int out_size, void* d_ws, size_t ws_size,
                              hipStream_t stream) {
  const float* x0 = (const float*)d_in[0];
  const float* x1 = (const float*)d_in[1];
  const float* W0 = (const float*)d_in[2];
  const float* b0 = (const float*)d_in[3];
  const float* V0 = (const float*)d_in[4];
  // d_in[5] = c0: cancels under antisymmetrization (sum of signs == 0)
  const float* W1 = (const float*)d_in[6];
  const float* b1 = (const float*)d_in[7];
  const float* V1 = (const float*)d_in[8];
  // d_in[9] = c1: cancels

  float* ws  = (float*)d_ws;      // 512 floats: psi partials [leaf][half][b]
  float* out = (float*)d_out;     // 256 floats: sign[128], logabs[128]

  antisym_leaf_kernel<<<512, 512, 0, stream>>>(x0, x1, W0, b0, V0, W1, b1, V1, ws);
  finalize_kernel<<<1, NB, 0, stream>>>(ws, out);
}